// Round 1
// baseline (318.139 us; speedup 1.0000x reference)
//
#include <hip/hip_runtime.h>

#define B_N 4096
#define F_N 1024
#define H_N 4
#define D_N 256
#define BF_ELEMS (B_N * F_N)   // 4194304

typedef unsigned short u16;
typedef __bf16 bf16x8 __attribute__((ext_vector_type(8)));
typedef float f32x4 __attribute__((ext_vector_type(4)));
typedef u16 u16x4 __attribute__((ext_vector_type(4)));

__device__ __forceinline__ u16 f2bf(float v) {
    union { float f; unsigned u; } x; x.f = v;
    unsigned r = x.u + 0x7fffu + ((x.u >> 16) & 1u);
    return (u16)(r >> 16);
}

__global__ void kzero_flag(int* flag) {
    if (threadIdx.x == 0) *flag = 0;
}

__global__ void kflag(const float* __restrict__ n, int* __restrict__ flag) {
    int idx = blockIdx.x * 256 + threadIdx.x;
    const f32x4 v = *(const f32x4*)(n + idx * 4);
    bool any = (v[0] != 0.f) || (v[1] != 0.f) || (v[2] != 0.f) || (v[3] != 0.f);
    if (__ballot(any)) {
        if ((threadIdx.x & 63) == 0) atomicOr(flag, 1);
    }
}

// conv step + state shift + bf16 conversions of conv_act / h / inputs
__global__ void kconv(const float* __restrict__ inputs, const float* __restrict__ cs,
                      const float* __restrict__ ck, const float* __restrict__ cb,
                      const float* __restrict__ h,
                      float* __restrict__ ncs_out, u16* __restrict__ convact,
                      u16* __restrict__ hbf, u16* __restrict__ inbf) {
    int idx = blockIdx.x * 256 + threadIdx.x;   // 0 .. 1M-1
    int flat = idx << 2;
    int b = flat >> 10;
    int f = flat & 1023;
    const f32x4 x  = *(const f32x4*)(inputs + flat);
    const f32x4 c1 = *(const f32x4*)(cs + b * 4096 + 1024 + f);
    const f32x4 c2 = *(const f32x4*)(cs + b * 4096 + 2048 + f);
    const f32x4 c3 = *(const f32x4*)(cs + b * 4096 + 3072 + f);
    const f32x4 k0 = *(const f32x4*)(ck + f);
    const f32x4 k1 = *(const f32x4*)(ck + 1024 + f);
    const f32x4 k2 = *(const f32x4*)(ck + 2048 + f);
    const f32x4 k3 = *(const f32x4*)(ck + 3072 + f);
    const f32x4 bias = *(const f32x4*)(cb + f);
    const f32x4 h4 = *(const f32x4*)(h + flat);

    u16x4 ca, hb, ib;
    #pragma unroll
    for (int q = 0; q < 4; ++q) {
        float v = c1[q] * k0[q] + c2[q] * k1[q] + c3[q] * k2[q] + x[q] * k3[q] + bias[q];
        float a = v / (1.f + expf(-v));   // silu
        ca[q] = f2bf(a);
        hb[q] = f2bf(h4[q]);
        ib[q] = f2bf(x[q]);
    }
    *(u16x4*)(convact + flat) = ca;
    *(u16x4*)(hbf + flat) = hb;
    *(u16x4*)(inbf + flat) = ib;

    float* ob = ncs_out + b * 4096 + f;
    *(f32x4*)(ob)        = c1;
    *(f32x4*)(ob + 1024) = c2;
    *(f32x4*)(ob + 2048) = c3;
    *(f32x4*)(ob + 3072) = x;
}

// f32 (H,D,D)[k][e] -> bf16 transposed [e][k], 8 matrices
__global__ void kconvw(const float* W0, const float* W1, const float* W2, const float* W3,
                       const float* W4, const float* W5, const float* W6, const float* W7,
                       u16* __restrict__ wt) {
    const float* tab[8] = {W0, W1, W2, W3, W4, W5, W6, W7};
    int mat = blockIdx.z;
    int hd = blockIdx.y;
    const float* src = tab[mat] + hd * 65536;
    u16* dst = wt + (mat * 4 + hd) * 65536;
    __shared__ float tile[32][33];
    int tx = threadIdx.x & 31, ty = threadIdx.x >> 5;
    int bx = (blockIdx.x & 7) * 32;   // e tile
    int by = (blockIdx.x >> 3) * 32;  // k tile
    #pragma unroll
    for (int r = 0; r < 4; ++r)
        tile[ty + r * 8][tx] = src[(by + ty + r * 8) * 256 + bx + tx];
    __syncthreads();
    #pragma unroll
    for (int r = 0; r < 4; ++r)
        dst[(bx + ty + r * 8) * 256 + by + tx] = f2bf(tile[tx][ty + r * 8]);
}

// gates[g][b][hd*256+e] = x_g . W_g + h . R_g   (no bias; added in kpoint)
// grid: x = 32 (M/128), y = 8 (n-tile: gate-half * 4 + e-tile), z = 8 (pass*4 + head)
__global__ __launch_bounds__(256) void kgemm(
    const u16* __restrict__ convact, const u16* __restrict__ inbf,
    const u16* __restrict__ hbf, const u16* __restrict__ wt,
    float* __restrict__ gates) {
    __shared__ u16 ldsA[128 * 32];
    __shared__ u16 ldsB[64 * 32];

    int t = threadIdx.x;
    int mtile = blockIdx.x;
    int nt = blockIdx.y;
    int z = blockIdx.z;
    int pass = z >> 2;
    int hd = z & 3;
    int gsel = pass * 2 + (nt >> 2);      // 0=i,1=f,2=z,3=o
    int e0 = (nt & 3) * 64;
    int row0 = mtile * 128;

    const u16* a0 = (pass ? inbf : convact) + row0 * 1024 + hd * 256;
    const u16* a1 = hbf + row0 * 1024 + hd * 256;
    const u16* b0 = wt + (gsel * 4 + hd) * 65536 + e0 * 256;         // W part
    const u16* b1 = wt + ((gsel + 4) * 4 + hd) * 65536 + e0 * 256;   // R part

    f32x4 acc[4][2];
    #pragma unroll
    for (int i = 0; i < 4; ++i)
        #pragma unroll
        for (int j = 0; j < 2; ++j)
            acc[i][j] = (f32x4){0.f, 0.f, 0.f, 0.f};

    int lane = t & 63;
    int lr = lane & 15, lk = lane >> 4;
    int w = t >> 6;
    int wm = w >> 1, wn = w & 1;
    int wbase = t & ~63;   // wave-uniform lane0 index

    for (int ks = 0; ks < 16; ++ks) {
        int kk = ks * 32;
        const u16* ap = (kk < 256) ? (a0 + kk) : (a1 + (kk - 256));
        const u16* bp = (kk < 256) ? (b0 + kk) : (b1 + (kk - 256));
        __syncthreads();
        // stage A: [128][32] bf16, 512 x 16B lane-loads in 2 rounds
        #pragma unroll
        for (int s = 0; s < 2; ++s) {
            int idx = t + s * 256;
            int row = idx >> 2, seg = idx & 3;
            __builtin_amdgcn_global_load_lds(
                (const __attribute__((address_space(1))) void*)(ap + row * 1024 + seg * 8),
                (__attribute__((address_space(3))) void*)(&ldsA[(wbase + s * 256) * 8]),
                16, 0, 0);
        }
        // stage B: [64 e][32 k] bf16 (weights pre-transposed)
        {
            int row = t >> 2, seg = t & 3;
            __builtin_amdgcn_global_load_lds(
                (const __attribute__((address_space(1))) void*)(bp + row * 256 + seg * 8),
                (__attribute__((address_space(3))) void*)(&ldsB[wbase * 8]),
                16, 0, 0);
        }
        __syncthreads();

        bf16x8 a[4], bfr[2];
        #pragma unroll
        for (int mi = 0; mi < 4; ++mi)
            a[mi] = *(const bf16x8*)&ldsA[(wm * 64 + mi * 16 + lr) * 32 + lk * 8];
        #pragma unroll
        for (int ni = 0; ni < 2; ++ni)
            bfr[ni] = *(const bf16x8*)&ldsB[(wn * 32 + ni * 16 + lr) * 32 + lk * 8];
        #pragma unroll
        for (int mi = 0; mi < 4; ++mi)
            #pragma unroll
            for (int ni = 0; ni < 2; ++ni)
                acc[mi][ni] = __builtin_amdgcn_mfma_f32_16x16x32_bf16(a[mi], bfr[ni], acc[mi][ni], 0, 0, 0);
    }

    float* gout = gates + (size_t)gsel * BF_ELEMS;
    #pragma unroll
    for (int mi = 0; mi < 4; ++mi)
        #pragma unroll
        for (int ni = 0; ni < 2; ++ni)
            #pragma unroll
            for (int r = 0; r < 4; ++r) {
                int row = row0 + wm * 64 + mi * 16 + lk * 4 + r;
                int col = hd * 256 + e0 + wn * 32 + ni * 16 + lr;
                gout[row * 1024 + col] = acc[mi][ni][r];
            }
}

// pointwise gate math + per-head LayerNorm; one block per row, one wave per head
__global__ __launch_bounds__(256) void kpoint(
    const float* __restrict__ gates,
    const float* __restrict__ c, const float* __restrict__ n, const float* __restrict__ m,
    const float* __restrict__ bgi, const float* __restrict__ bgf,
    const float* __restrict__ bgz, const float* __restrict__ bgo,
    const float* __restrict__ ln_scale, const int* __restrict__ flagp,
    float* __restrict__ out) {
    int b = blockIdx.x;
    int t = threadIdx.x;
    int l = t & 63;
    int j = (t >> 6) * 256 + l * 4;
    int idx = b * 1024 + j;
    int flag = *flagp;

    f32x4 iv = *(const f32x4*)(gates + idx);
    f32x4 fv = *(const f32x4*)(gates + (size_t)BF_ELEMS + idx);
    f32x4 zv = *(const f32x4*)(gates + 2 * (size_t)BF_ELEMS + idx);
    f32x4 ov = *(const f32x4*)(gates + 3 * (size_t)BF_ELEMS + idx);
    f32x4 b_i = *(const f32x4*)(bgi + j);
    f32x4 b_f = *(const f32x4*)(bgf + j);
    f32x4 b_z = *(const f32x4*)(bgz + j);
    f32x4 b_o = *(const f32x4*)(bgo + j);
    f32x4 cv = *(const f32x4*)(c + idx);
    f32x4 nv = *(const f32x4*)(n + idx);
    f32x4 mv = *(const f32x4*)(m + idx);
    f32x4 sc = *(const f32x4*)(ln_scale + j);

    f32x4 cn, nn, mn, hn;
    float s = 0.f, ss = 0.f;
    #pragma unroll
    for (int q = 0; q < 4; ++q) {
        float I = iv[q] + b_i[q];
        float Fg = fv[q] + b_f[q];
        float Z = zv[q] + b_z[q];
        float O = ov[q] + b_o[q];
        float og = 1.f / (1.f + expf(-O));
        float lf = (Fg >= 0.f) ? -log1pf(expf(-Fg)) : (Fg - log1pf(expf(Fg)));
        float mnew = flag ? fmaxf(lf + mv[q], I) : I;
        float ip = fminf(expf(I - mnew), 1.f);
        float fp = fminf(expf(lf + mv[q] - mnew), 1.f);
        float cnew = fp * cv[q] + ip * tanhf(Z);
        float nnew = fp * nv[q] + ip;
        float hnew = og * (cnew / fmaxf(nnew, 1e-6f));
        cn[q] = cnew; nn[q] = nnew; mn[q] = mnew; hn[q] = hnew;
        s += hnew; ss += hnew * hnew;
    }
    #pragma unroll
    for (int off = 32; off >= 1; off >>= 1) {
        s  += __shfl_xor(s, off);
        ss += __shfl_xor(ss, off);
    }
    float mu = s * (1.f / 256.f);
    float var = ss * (1.f / 256.f) - mu * mu;
    float rs = rsqrtf(var + 1e-6f);

    f32x4 o4;
    #pragma unroll
    for (int q = 0; q < 4; ++q)
        o4[q] = (hn[q] - mu) * rs * sc[q];

    *(f32x4*)(out + idx) = o4;
    *(f32x4*)(out + (size_t)BF_ELEMS + idx) = cn;
    *(f32x4*)(out + 2 * (size_t)BF_ELEMS + idx) = nn;
    *(f32x4*)(out + 3 * (size_t)BF_ELEMS + idx) = mn;
    *(f32x4*)(out + 4 * (size_t)BF_ELEMS + idx) = hn;
}

extern "C" void kernel_launch(void* const* d_in, const int* in_sizes, int n_in,
                              void* d_out, int out_size, void* d_ws, size_t ws_size,
                              hipStream_t stream) {
    const float* inputs = (const float*)d_in[0];
    const float* c = (const float*)d_in[1];
    const float* n = (const float*)d_in[2];
    const float* m = (const float*)d_in[3];
    const float* h = (const float*)d_in[4];
    const float* conv_state = (const float*)d_in[5];
    const float* conv_kernel = (const float*)d_in[6];
    const float* conv_bias = (const float*)d_in[7];
    const float* W[8];
    for (int i = 0; i < 8; ++i) W[i] = (const float*)d_in[8 + i];
    const float* bgi = (const float*)d_in[16];
    const float* bgf = (const float*)d_in[17];
    const float* bgz = (const float*)d_in[18];
    const float* bgo = (const float*)d_in[19];
    const float* ln_scale = (const float*)d_in[20];
    float* out = (float*)d_out;

    char* ws = (char*)d_ws;
    int* flag = (int*)ws;
    u16* convact = (u16*)(ws + 256);
    u16* hbf = convact + BF_ELEMS;
    u16* inbf = hbf + BF_ELEMS;
    u16* wt = inbf + BF_ELEMS;                       // 8*4*65536 bf16
    float* gates = (float*)(ws + 256 + (size_t)3 * BF_ELEMS * 2 + (size_t)8 * 4 * 65536 * 2);

    kzero_flag<<<1, 64, 0, stream>>>(flag);
    kflag<<<4096, 256, 0, stream>>>(n, flag);
    kconv<<<4096, 256, 0, stream>>>(inputs, conv_state, conv_kernel, conv_bias, h,
                                    out + 5 * (size_t)BF_ELEMS, convact, hbf, inbf);
    kconvw<<<dim3(64, 4, 8), 256, 0, stream>>>(W[0], W[1], W[2], W[3], W[4], W[5], W[6], W[7], wt);
    kgemm<<<dim3(32, 8, 8), 256, 0, stream>>>(convact, inbf, hbf, wt, gates);
    kpoint<<<4096, 256, 0, stream>>>(gates, c, n, m, bgi, bgf, bgz, bgo, ln_scale, flag, out);
}

// Round 2
// 135.401 us; speedup vs baseline: 2.3496x; 2.3496x over previous
//
#include <hip/hip_runtime.h>

#define B_N 4096
#define F_N 1024
#define H_N 4
#define D_N 256
#define BF_ELEMS (B_N * F_N)   // 4194304

typedef unsigned short u16;
typedef __bf16 bf16x8 __attribute__((ext_vector_type(8)));
typedef float f32x4 __attribute__((ext_vector_type(4)));
typedef u16 u16x4 __attribute__((ext_vector_type(4)));

__device__ __forceinline__ u16 f2bf(float v) {
    union { float f; unsigned u; } x; x.f = v;
    unsigned r = x.u + 0x7fffu + ((x.u >> 16) & 1u);
    return (u16)(r >> 16);
}

__global__ void kzero_flag(int* flag) {
    if (threadIdx.x == 0) *flag = 0;
}

// any(n != 0) -> flag. Benign race: only value 1 is ever stored, so a plain
// conditional store (one lane per wave) replaces the 16K-deep atomic queue
// that serialized at one L2 bank (was 189 us).
__global__ void kflag(const float* __restrict__ n, int* __restrict__ flag) {
    int idx = blockIdx.x * 256 + threadIdx.x;
    const f32x4 v = *(const f32x4*)(n + idx * 4);
    bool any = (v[0] != 0.f) || (v[1] != 0.f) || (v[2] != 0.f) || (v[3] != 0.f);
    unsigned long long msk = __ballot(any);
    if (msk && (threadIdx.x & 63) == 0) *flag = 1;
}

// conv step + state shift + bf16 conversions of conv_act / h / inputs
__global__ void kconv(const float* __restrict__ inputs, const float* __restrict__ cs,
                      const float* __restrict__ ck, const float* __restrict__ cb,
                      const float* __restrict__ h,
                      float* __restrict__ ncs_out, u16* __restrict__ convact,
                      u16* __restrict__ hbf, u16* __restrict__ inbf) {
    int idx = blockIdx.x * 256 + threadIdx.x;   // 0 .. 1M-1
    int flat = idx << 2;
    int b = flat >> 10;
    int f = flat & 1023;
    const f32x4 x  = *(const f32x4*)(inputs + flat);
    const f32x4 c1 = *(const f32x4*)(cs + b * 4096 + 1024 + f);
    const f32x4 c2 = *(const f32x4*)(cs + b * 4096 + 2048 + f);
    const f32x4 c3 = *(const f32x4*)(cs + b * 4096 + 3072 + f);
    const f32x4 k0 = *(const f32x4*)(ck + f);
    const f32x4 k1 = *(const f32x4*)(ck + 1024 + f);
    const f32x4 k2 = *(const f32x4*)(ck + 2048 + f);
    const f32x4 k3 = *(const f32x4*)(ck + 3072 + f);
    const f32x4 bias = *(const f32x4*)(cb + f);
    const f32x4 h4 = *(const f32x4*)(h + flat);

    u16x4 ca, hb, ib;
    #pragma unroll
    for (int q = 0; q < 4; ++q) {
        float v = c1[q] * k0[q] + c2[q] * k1[q] + c3[q] * k2[q] + x[q] * k3[q] + bias[q];
        float a = v / (1.f + expf(-v));   // silu
        ca[q] = f2bf(a);
        hb[q] = f2bf(h4[q]);
        ib[q] = f2bf(x[q]);
    }
    *(u16x4*)(convact + flat) = ca;
    *(u16x4*)(hbf + flat) = hb;
    *(u16x4*)(inbf + flat) = ib;

    float* ob = ncs_out + b * 4096 + f;
    *(f32x4*)(ob)        = c1;
    *(f32x4*)(ob + 1024) = c2;
    *(f32x4*)(ob + 2048) = c3;
    *(f32x4*)(ob + 3072) = x;
}

// f32 (H,D,D)[k][e] -> bf16 transposed [e][k], 8 matrices
__global__ void kconvw(const float* W0, const float* W1, const float* W2, const float* W3,
                       const float* W4, const float* W5, const float* W6, const float* W7,
                       u16* __restrict__ wt) {
    const float* tab[8] = {W0, W1, W2, W3, W4, W5, W6, W7};
    int mat = blockIdx.z;
    int hd = blockIdx.y;
    const float* src = tab[mat] + hd * 65536;
    u16* dst = wt + (mat * 4 + hd) * 65536;
    __shared__ float tile[32][33];
    int tx = threadIdx.x & 31, ty = threadIdx.x >> 5;
    int bx = (blockIdx.x & 7) * 32;   // e tile
    int by = (blockIdx.x >> 3) * 32;  // k tile
    #pragma unroll
    for (int r = 0; r < 4; ++r)
        tile[ty + r * 8][tx] = src[(by + ty + r * 8) * 256 + bx + tx];
    __syncthreads();
    #pragma unroll
    for (int r = 0; r < 4; ++r)
        dst[(bx + ty + r * 8) * 256 + by + tx] = f2bf(tile[tx][ty + r * 8]);
}

// gates[g][b][hd*256+e] = x_g . W_g + h . R_g   (no bias; added in kpoint)
// grid: x = 32 (M/128), y = 8 (n-tile: gate-half * 4 + e-tile), z = 8 (pass*4 + head)
__global__ __launch_bounds__(256) void kgemm(
    const u16* __restrict__ convact, const u16* __restrict__ inbf,
    const u16* __restrict__ hbf, const u16* __restrict__ wt,
    float* __restrict__ gates) {
    __shared__ u16 ldsA[128 * 32];
    __shared__ u16 ldsB[64 * 32];

    int t = threadIdx.x;
    int mtile = blockIdx.x;
    int nt = blockIdx.y;
    int z = blockIdx.z;
    int pass = z >> 2;
    int hd = z & 3;
    int gsel = pass * 2 + (nt >> 2);      // 0=i,1=f,2=z,3=o
    int e0 = (nt & 3) * 64;
    int row0 = mtile * 128;

    const u16* a0 = (pass ? inbf : convact) + row0 * 1024 + hd * 256;
    const u16* a1 = hbf + row0 * 1024 + hd * 256;
    const u16* b0 = wt + (gsel * 4 + hd) * 65536 + e0 * 256;         // W part
    const u16* b1 = wt + ((gsel + 4) * 4 + hd) * 65536 + e0 * 256;   // R part

    f32x4 acc[4][2];
    #pragma unroll
    for (int i = 0; i < 4; ++i)
        #pragma unroll
        for (int j = 0; j < 2; ++j)
            acc[i][j] = (f32x4){0.f, 0.f, 0.f, 0.f};

    int lane = t & 63;
    int lr = lane & 15, lk = lane >> 4;
    int w = t >> 6;
    int wm = w >> 1, wn = w & 1;
    int wbase = t & ~63;   // wave-uniform lane0 index

    for (int ks = 0; ks < 16; ++ks) {
        int kk = ks * 32;
        const u16* ap = (kk < 256) ? (a0 + kk) : (a1 + (kk - 256));
        const u16* bp = (kk < 256) ? (b0 + kk) : (b1 + (kk - 256));
        __syncthreads();
        // stage A: [128][32] bf16, 512 x 16B lane-loads in 2 rounds
        #pragma unroll
        for (int s = 0; s < 2; ++s) {
            int idx = t + s * 256;
            int row = idx >> 2, seg = idx & 3;
            __builtin_amdgcn_global_load_lds(
                (const __attribute__((address_space(1))) void*)(ap + row * 1024 + seg * 8),
                (__attribute__((address_space(3))) void*)(&ldsA[(wbase + s * 256) * 8]),
                16, 0, 0);
        }
        // stage B: [64 e][32 k] bf16 (weights pre-transposed)
        {
            int row = t >> 2, seg = t & 3;
            __builtin_amdgcn_global_load_lds(
                (const __attribute__((address_space(1))) void*)(bp + row * 256 + seg * 8),
                (__attribute__((address_space(3))) void*)(&ldsB[wbase * 8]),
                16, 0, 0);
        }
        __syncthreads();

        bf16x8 a[4], bfr[2];
        #pragma unroll
        for (int mi = 0; mi < 4; ++mi)
            a[mi] = *(const bf16x8*)&ldsA[(wm * 64 + mi * 16 + lr) * 32 + lk * 8];
        #pragma unroll
        for (int ni = 0; ni < 2; ++ni)
            bfr[ni] = *(const bf16x8*)&ldsB[(wn * 32 + ni * 16 + lr) * 32 + lk * 8];
        #pragma unroll
        for (int mi = 0; mi < 4; ++mi)
            #pragma unroll
            for (int ni = 0; ni < 2; ++ni)
                acc[mi][ni] = __builtin_amdgcn_mfma_f32_16x16x32_bf16(a[mi], bfr[ni], acc[mi][ni], 0, 0, 0);
    }

    float* gout = gates + (size_t)gsel * BF_ELEMS;
    #pragma unroll
    for (int mi = 0; mi < 4; ++mi)
        #pragma unroll
        for (int ni = 0; ni < 2; ++ni)
            #pragma unroll
            for (int r = 0; r < 4; ++r) {
                int row = row0 + wm * 64 + mi * 16 + lk * 4 + r;
                int col = hd * 256 + e0 + wn * 32 + ni * 16 + lr;
                gout[row * 1024 + col] = acc[mi][ni][r];
            }
}

// pointwise gate math + per-head LayerNorm; one block per row, one wave per head
__global__ __launch_bounds__(256) void kpoint(
    const float* __restrict__ gates,
    const float* __restrict__ c, const float* __restrict__ n, const float* __restrict__ m,
    const float* __restrict__ bgi, const float* __restrict__ bgf,
    const float* __restrict__ bgz, const float* __restrict__ bgo,
    const float* __restrict__ ln_scale, const int* __restrict__ flagp,
    float* __restrict__ out) {
    int b = blockIdx.x;
    int t = threadIdx.x;
    int l = t & 63;
    int j = (t >> 6) * 256 + l * 4;
    int idx = b * 1024 + j;
    int flag = *flagp;

    f32x4 iv = *(const f32x4*)(gates + idx);
    f32x4 fv = *(const f32x4*)(gates + (size_t)BF_ELEMS + idx);
    f32x4 zv = *(const f32x4*)(gates + 2 * (size_t)BF_ELEMS + idx);
    f32x4 ov = *(const f32x4*)(gates + 3 * (size_t)BF_ELEMS + idx);
    f32x4 b_i = *(const f32x4*)(bgi + j);
    f32x4 b_f = *(const f32x4*)(bgf + j);
    f32x4 b_z = *(const f32x4*)(bgz + j);
    f32x4 b_o = *(const f32x4*)(bgo + j);
    f32x4 cv = *(const f32x4*)(c + idx);
    f32x4 nv = *(const f32x4*)(n + idx);
    f32x4 mv = *(const f32x4*)(m + idx);
    f32x4 sc = *(const f32x4*)(ln_scale + j);

    f32x4 cn, nn, mn, hn;
    float s = 0.f, ss = 0.f;
    #pragma unroll
    for (int q = 0; q < 4; ++q) {
        float I = iv[q] + b_i[q];
        float Fg = fv[q] + b_f[q];
        float Z = zv[q] + b_z[q];
        float O = ov[q] + b_o[q];
        float og = 1.f / (1.f + expf(-O));
        float lf = (Fg >= 0.f) ? -log1pf(expf(-Fg)) : (Fg - log1pf(expf(Fg)));
        float mnew = flag ? fmaxf(lf + mv[q], I) : I;
        float ip = fminf(expf(I - mnew), 1.f);
        float fp = fminf(expf(lf + mv[q] - mnew), 1.f);
        float cnew = fp * cv[q] + ip * tanhf(Z);
        float nnew = fp * nv[q] + ip;
        float hnew = og * (cnew / fmaxf(nnew, 1e-6f));
        cn[q] = cnew; nn[q] = nnew; mn[q] = mnew; hn[q] = hnew;
        s += hnew; ss += hnew * hnew;
    }
    #pragma unroll
    for (int off = 32; off >= 1; off >>= 1) {
        s  += __shfl_xor(s, off);
        ss += __shfl_xor(ss, off);
    }
    float mu = s * (1.f / 256.f);
    float var = ss * (1.f / 256.f) - mu * mu;
    float rs = rsqrtf(var + 1e-6f);

    f32x4 o4;
    #pragma unroll
    for (int q = 0; q < 4; ++q)
        o4[q] = (hn[q] - mu) * rs * sc[q];

    *(f32x4*)(out + idx) = o4;
    *(f32x4*)(out + (size_t)BF_ELEMS + idx) = cn;
    *(f32x4*)(out + 2 * (size_t)BF_ELEMS + idx) = nn;
    *(f32x4*)(out + 3 * (size_t)BF_ELEMS + idx) = mn;
    *(f32x4*)(out + 4 * (size_t)BF_ELEMS + idx) = hn;
}

extern "C" void kernel_launch(void* const* d_in, const int* in_sizes, int n_in,
                              void* d_out, int out_size, void* d_ws, size_t ws_size,
                              hipStream_t stream) {
    const float* inputs = (const float*)d_in[0];
    const float* c = (const float*)d_in[1];
    const float* n = (const float*)d_in[2];
    const float* m = (const float*)d_in[3];
    const float* h = (const float*)d_in[4];
    const float* conv_state = (const float*)d_in[5];
    const float* conv_kernel = (const float*)d_in[6];
    const float* conv_bias = (const float*)d_in[7];
    const float* W[8];
    for (int i = 0; i < 8; ++i) W[i] = (const float*)d_in[8 + i];
    const float* bgi = (const float*)d_in[16];
    const float* bgf = (const float*)d_in[17];
    const float* bgz = (const float*)d_in[18];
    const float* bgo = (const float*)d_in[19];
    const float* ln_scale = (const float*)d_in[20];
    float* out = (float*)d_out;

    char* ws = (char*)d_ws;
    int* flag = (int*)ws;
    u16* convact = (u16*)(ws + 256);
    u16* hbf = convact + BF_ELEMS;
    u16* inbf = hbf + BF_ELEMS;
    u16* wt = inbf + BF_ELEMS;                       // 8*4*65536 bf16
    float* gates = (float*)(ws + 256 + (size_t)3 * BF_ELEMS * 2 + (size_t)8 * 4 * 65536 * 2);

    kzero_flag<<<1, 64, 0, stream>>>(flag);
    kflag<<<4096, 256, 0, stream>>>(n, flag);
    kconv<<<4096, 256, 0, stream>>>(inputs, conv_state, conv_kernel, conv_bias, h,
                                    out + 5 * (size_t)BF_ELEMS, convact, hbf, inbf);
    kconvw<<<dim3(64, 4, 8), 256, 0, stream>>>(W[0], W[1], W[2], W[3], W[4], W[5], W[6], W[7], wt);
    kgemm<<<dim3(32, 8, 8), 256, 0, stream>>>(convact, inbf, hbf, wt, gates);
    kpoint<<<4096, 256, 0, stream>>>(gates, c, n, m, bgi, bgf, bgz, bgo, ln_scale, flag, out);
}

// Round 3
// 127.048 us; speedup vs baseline: 2.5041x; 1.0657x over previous
//
#include <hip/hip_runtime.h>

#define B_N 4096
#define F_N 1024
#define H_N 4
#define D_N 256
#define BF_ELEMS (B_N * F_N)   // 4194304

typedef unsigned short u16;
typedef __bf16 bf16x8 __attribute__((ext_vector_type(8)));
typedef float f32x4 __attribute__((ext_vector_type(4)));
typedef u16 u16x4 __attribute__((ext_vector_type(4)));

__device__ __forceinline__ u16 f2bf(float v) {
    union { float f; unsigned u; } x; x.f = v;
    unsigned r = x.u + 0x7fffu + ((x.u >> 16) & 1u);
    return (u16)(r >> 16);
}

__device__ __forceinline__ float bf2f(u16 v) {
    union { unsigned u; float f; } x; x.u = ((unsigned)v) << 16;
    return x.f;
}

__global__ void kzero_flag(int* flag) {
    if (threadIdx.x == 0) *flag = 0;
}

// any(n != 0) -> flag. Benign race: only 1 is ever stored (plain store, one
// lane per wave) — the single-address atomic queue was 189 us in round 1.
__global__ void kflag(const float* __restrict__ n, int* __restrict__ flag) {
    int idx = blockIdx.x * 256 + threadIdx.x;
    const f32x4 v = *(const f32x4*)(n + idx * 4);
    bool any = (v[0] != 0.f) || (v[1] != 0.f) || (v[2] != 0.f) || (v[3] != 0.f);
    unsigned long long msk = __ballot(any);
    if (msk && (threadIdx.x & 63) == 0) *flag = 1;
}

// conv step + state shift + bf16 conversions of conv_act / h / inputs
__global__ void kconv(const float* __restrict__ inputs, const float* __restrict__ cs,
                      const float* __restrict__ ck, const float* __restrict__ cb,
                      const float* __restrict__ h,
                      float* __restrict__ ncs_out, u16* __restrict__ convact,
                      u16* __restrict__ hbf, u16* __restrict__ inbf) {
    int idx = blockIdx.x * 256 + threadIdx.x;   // 0 .. 1M-1
    int flat = idx << 2;
    int b = flat >> 10;
    int f = flat & 1023;
    const f32x4 x  = *(const f32x4*)(inputs + flat);
    const f32x4 c1 = *(const f32x4*)(cs + b * 4096 + 1024 + f);
    const f32x4 c2 = *(const f32x4*)(cs + b * 4096 + 2048 + f);
    const f32x4 c3 = *(const f32x4*)(cs + b * 4096 + 3072 + f);
    const f32x4 k0 = *(const f32x4*)(ck + f);
    const f32x4 k1 = *(const f32x4*)(ck + 1024 + f);
    const f32x4 k2 = *(const f32x4*)(ck + 2048 + f);
    const f32x4 k3 = *(const f32x4*)(ck + 3072 + f);
    const f32x4 bias = *(const f32x4*)(cb + f);
    const f32x4 h4 = *(const f32x4*)(h + flat);

    u16x4 ca, hb, ib;
    #pragma unroll
    for (int q = 0; q < 4; ++q) {
        float v = c1[q] * k0[q] + c2[q] * k1[q] + c3[q] * k2[q] + x[q] * k3[q] + bias[q];
        float a = v / (1.f + expf(-v));   // silu
        ca[q] = f2bf(a);
        hb[q] = f2bf(h4[q]);
        ib[q] = f2bf(x[q]);
    }
    *(u16x4*)(convact + flat) = ca;
    *(u16x4*)(hbf + flat) = hb;
    *(u16x4*)(inbf + flat) = ib;

    float* ob = ncs_out + b * 4096 + f;
    *(f32x4*)(ob)        = c1;
    *(f32x4*)(ob + 1024) = c2;
    *(f32x4*)(ob + 2048) = c3;
    *(f32x4*)(ob + 3072) = x;
}

// f32 (H,D,D)[k][e] -> bf16 transposed [e][k], 8 matrices
__global__ void kconvw(const float* W0, const float* W1, const float* W2, const float* W3,
                       const float* W4, const float* W5, const float* W6, const float* W7,
                       u16* __restrict__ wt) {
    const float* tab[8] = {W0, W1, W2, W3, W4, W5, W6, W7};
    int mat = blockIdx.z;
    int hd = blockIdx.y;
    const float* src = tab[mat] + hd * 65536;
    u16* dst = wt + (mat * 4 + hd) * 65536;
    __shared__ float tile[32][33];
    int tx = threadIdx.x & 31, ty = threadIdx.x >> 5;
    int bx = (blockIdx.x & 7) * 32;   // e tile
    int by = (blockIdx.x >> 3) * 32;  // k tile
    #pragma unroll
    for (int r = 0; r < 4; ++r)
        tile[ty + r * 8][tx] = src[(by + ty + r * 8) * 256 + bx + tx];
    __syncthreads();
    #pragma unroll
    for (int r = 0; r < 4; ++r)
        dst[(bx + ty + r * 8) * 256 + by + tx] = f2bf(tile[tx][ty + r * 8]);
}

// gates16[g][b][hd*256+e] = bf16( x_g . W_g + h . R_g + b_g )
// grid: x = 32 (M/128), y = 4 (gate-half*2 + e-tile of 128), z = 8 (pass*4 + head)
__global__ __launch_bounds__(256) void kgemm(
    const u16* __restrict__ convact, const u16* __restrict__ inbf,
    const u16* __restrict__ hbf, const u16* __restrict__ wt,
    const float* __restrict__ bgi, const float* __restrict__ bgf,
    const float* __restrict__ bgz, const float* __restrict__ bgo,
    u16* __restrict__ gates16) {
    __shared__ u16 ldsA[128 * 32];
    __shared__ u16 ldsB[128 * 32];

    int t = threadIdx.x;
    int mtile = blockIdx.x;
    int nt = blockIdx.y;
    int z = blockIdx.z;
    int pass = z >> 2;
    int hd = z & 3;
    int gsel = pass * 2 + (nt >> 1);      // 0=i,1=f,2=z,3=o
    int e0 = (nt & 1) * 128;
    int row0 = mtile * 128;

    const u16* a0 = (pass ? inbf : convact) + row0 * 1024 + hd * 256;
    const u16* a1 = hbf + row0 * 1024 + hd * 256;
    const u16* b0 = wt + (gsel * 4 + hd) * 65536 + e0 * 256;         // W part
    const u16* b1 = wt + ((gsel + 4) * 4 + hd) * 65536 + e0 * 256;   // R part
    const float* btab[4] = {bgi, bgf, bgz, bgo};
    const float* bias = btab[gsel] + hd * 256 + e0;

    f32x4 acc[4][4];
    #pragma unroll
    for (int i = 0; i < 4; ++i)
        #pragma unroll
        for (int j = 0; j < 4; ++j)
            acc[i][j] = (f32x4){0.f, 0.f, 0.f, 0.f};

    int lane = t & 63;
    int lr = lane & 15, lk = lane >> 4;
    int w = t >> 6;
    int wm = w >> 1, wn = w & 1;
    int wbase = t & ~63;   // wave-uniform lane0 index

    for (int ks = 0; ks < 16; ++ks) {
        int kk = ks * 32;
        const u16* ap = (kk < 256) ? (a0 + kk) : (a1 + (kk - 256));
        const u16* bp = (kk < 256) ? (b0 + kk) : (b1 + (kk - 256));
        __syncthreads();
        // stage A: [128 rows][32 k] bf16, 2 rounds of 256 x 16B lane-loads
        #pragma unroll
        for (int s = 0; s < 2; ++s) {
            int idx = t + s * 256;
            int row = idx >> 2, seg = idx & 3;
            __builtin_amdgcn_global_load_lds(
                (const __attribute__((address_space(1))) void*)(ap + row * 1024 + seg * 8),
                (__attribute__((address_space(3))) void*)(&ldsA[(wbase + s * 256) * 8]),
                16, 0, 0);
        }
        // stage B: [128 e][32 k] bf16 (weights pre-transposed), 2 rounds
        #pragma unroll
        for (int s = 0; s < 2; ++s) {
            int idx = t + s * 256;
            int row = idx >> 2, seg = idx & 3;
            __builtin_amdgcn_global_load_lds(
                (const __attribute__((address_space(1))) void*)(bp + row * 256 + seg * 8),
                (__attribute__((address_space(3))) void*)(&ldsB[(wbase + s * 256) * 8]),
                16, 0, 0);
        }
        __syncthreads();

        bf16x8 a[4], bfr[4];
        #pragma unroll
        for (int mi = 0; mi < 4; ++mi)
            a[mi] = *(const bf16x8*)&ldsA[(wm * 64 + mi * 16 + lr) * 32 + lk * 8];
        #pragma unroll
        for (int ni = 0; ni < 4; ++ni)
            bfr[ni] = *(const bf16x8*)&ldsB[(wn * 64 + ni * 16 + lr) * 32 + lk * 8];
        #pragma unroll
        for (int mi = 0; mi < 4; ++mi)
            #pragma unroll
            for (int ni = 0; ni < 4; ++ni)
                acc[mi][ni] = __builtin_amdgcn_mfma_f32_16x16x32_bf16(a[mi], bfr[ni], acc[mi][ni], 0, 0, 0);
    }

    // epilogue: + bias, convert bf16, store
    float bv[4];
    #pragma unroll
    for (int ni = 0; ni < 4; ++ni)
        bv[ni] = bias[wn * 64 + ni * 16 + lr];

    u16* gout = gates16 + (size_t)gsel * BF_ELEMS;
    #pragma unroll
    for (int mi = 0; mi < 4; ++mi)
        #pragma unroll
        for (int ni = 0; ni < 4; ++ni)
            #pragma unroll
            for (int r = 0; r < 4; ++r) {
                int row = row0 + wm * 64 + mi * 16 + lk * 4 + r;
                int col = hd * 256 + e0 + wn * 64 + ni * 16 + lr;
                gout[row * 1024 + col] = f2bf(acc[mi][ni][r] + bv[ni]);
            }
}

// pointwise gate math + per-head LayerNorm; one block per row, one wave per head
__global__ __launch_bounds__(256) void kpoint(
    const u16* __restrict__ gates16,
    const float* __restrict__ c, const float* __restrict__ n, const float* __restrict__ m,
    const float* __restrict__ ln_scale, const int* __restrict__ flagp,
    float* __restrict__ out) {
    int b = blockIdx.x;
    int t = threadIdx.x;
    int l = t & 63;
    int j = (t >> 6) * 256 + l * 4;
    int idx = b * 1024 + j;
    int flag = *flagp;

    u16x4 iv = *(const u16x4*)(gates16 + idx);
    u16x4 fv = *(const u16x4*)(gates16 + (size_t)BF_ELEMS + idx);
    u16x4 zv = *(const u16x4*)(gates16 + 2 * (size_t)BF_ELEMS + idx);
    u16x4 ov = *(const u16x4*)(gates16 + 3 * (size_t)BF_ELEMS + idx);
    f32x4 cv = *(const f32x4*)(c + idx);
    f32x4 nv = *(const f32x4*)(n + idx);
    f32x4 mv = *(const f32x4*)(m + idx);
    f32x4 sc = *(const f32x4*)(ln_scale + j);

    f32x4 cn, nn, mn, hn;
    float s = 0.f, ss = 0.f;
    #pragma unroll
    for (int q = 0; q < 4; ++q) {
        float I = bf2f(iv[q]);
        float Fg = bf2f(fv[q]);
        float Z = bf2f(zv[q]);
        float O = bf2f(ov[q]);
        float og = 1.f / (1.f + expf(-O));
        float lf = (Fg >= 0.f) ? -log1pf(expf(-Fg)) : (Fg - log1pf(expf(Fg)));
        float mnew = flag ? fmaxf(lf + mv[q], I) : I;
        float ip = fminf(expf(I - mnew), 1.f);
        float fp = fminf(expf(lf + mv[q] - mnew), 1.f);
        float cnew = fp * cv[q] + ip * tanhf(Z);
        float nnew = fp * nv[q] + ip;
        float hnew = og * (cnew / fmaxf(nnew, 1e-6f));
        cn[q] = cnew; nn[q] = nnew; mn[q] = mnew; hn[q] = hnew;
        s += hnew; ss += hnew * hnew;
    }
    #pragma unroll
    for (int off = 32; off >= 1; off >>= 1) {
        s  += __shfl_xor(s, off);
        ss += __shfl_xor(ss, off);
    }
    float mu = s * (1.f / 256.f);
    float var = ss * (1.f / 256.f) - mu * mu;
    float rs = rsqrtf(var + 1e-6f);

    f32x4 o4;
    #pragma unroll
    for (int q = 0; q < 4; ++q)
        o4[q] = (hn[q] - mu) * rs * sc[q];

    *(f32x4*)(out + idx) = o4;
    *(f32x4*)(out + (size_t)BF_ELEMS + idx) = cn;
    *(f32x4*)(out + 2 * (size_t)BF_ELEMS + idx) = nn;
    *(f32x4*)(out + 3 * (size_t)BF_ELEMS + idx) = mn;
    *(f32x4*)(out + 4 * (size_t)BF_ELEMS + idx) = hn;
}

extern "C" void kernel_launch(void* const* d_in, const int* in_sizes, int n_in,
                              void* d_out, int out_size, void* d_ws, size_t ws_size,
                              hipStream_t stream) {
    const float* inputs = (const float*)d_in[0];
    const float* c = (const float*)d_in[1];
    const float* n = (const float*)d_in[2];
    const float* m = (const float*)d_in[3];
    const float* h = (const float*)d_in[4];
    const float* conv_state = (const float*)d_in[5];
    const float* conv_kernel = (const float*)d_in[6];
    const float* conv_bias = (const float*)d_in[7];
    const float* W[8];
    for (int i = 0; i < 8; ++i) W[i] = (const float*)d_in[8 + i];
    const float* bgi = (const float*)d_in[16];
    const float* bgf = (const float*)d_in[17];
    const float* bgz = (const float*)d_in[18];
    const float* bgo = (const float*)d_in[19];
    const float* ln_scale = (const float*)d_in[20];
    float* out = (float*)d_out;

    char* ws = (char*)d_ws;
    int* flag = (int*)ws;
    u16* convact = (u16*)(ws + 256);
    u16* hbf = convact + BF_ELEMS;
    u16* inbf = hbf + BF_ELEMS;
    u16* wt = inbf + BF_ELEMS;                       // 8*4*65536 bf16
    u16* gates16 = wt + (size_t)8 * 4 * 65536;       // 4 * BF_ELEMS bf16

    kzero_flag<<<1, 64, 0, stream>>>(flag);
    kflag<<<4096, 256, 0, stream>>>(n, flag);
    kconv<<<4096, 256, 0, stream>>>(inputs, conv_state, conv_kernel, conv_bias, h,
                                    out + 5 * (size_t)BF_ELEMS, convact, hbf, inbf);
    kconvw<<<dim3(64, 4, 8), 256, 0, stream>>>(W[0], W[1], W[2], W[3], W[4], W[5], W[6], W[7], wt);
    kgemm<<<dim3(32, 4, 8), 256, 0, stream>>>(convact, inbf, hbf, wt,
                                              bgi, bgf, bgz, bgo, gates16);
    kpoint<<<4096, 256, 0, stream>>>(gates16, c, n, m, ln_scale, flag, out);
}

// Round 4
// 114.354 us; speedup vs baseline: 2.7821x; 1.1110x over previous
//
#include <hip/hip_runtime.h>

#define B_N 4096
#define F_N 1024
#define H_N 4
#define D_N 256
#define BF_ELEMS (B_N * F_N)   // 4194304

typedef unsigned short u16;
typedef __bf16 bf16x8 __attribute__((ext_vector_type(8)));
typedef float f32x4 __attribute__((ext_vector_type(4)));
typedef u16 u16x4 __attribute__((ext_vector_type(4)));

__device__ __forceinline__ u16 f2bf(float v) {
    union { float f; unsigned u; } x; x.f = v;
    unsigned r = x.u + 0x7fffu + ((x.u >> 16) & 1u);
    return (u16)(r >> 16);
}

__device__ __forceinline__ float bf2f(u16 v) {
    union { unsigned u; float f; } x; x.u = ((unsigned)v) << 16;
    return x.f;
}

// Fused prep: blocks 0..4095 = conv step + state shift + flag + bf16 casts;
// blocks 4096..6143 = weight f32->bf16 transpose [k][e] -> [e][k].
__global__ __launch_bounds__(256) void kprep(
    const float* __restrict__ inputs, const float* __restrict__ cs,
    const float* __restrict__ ck, const float* __restrict__ cb,
    const float* __restrict__ h, const float* __restrict__ n,
    const float* W0, const float* W1, const float* W2, const float* W3,
    const float* W4, const float* W5, const float* W6, const float* W7,
    float* __restrict__ ncs_out, u16* __restrict__ convact,
    u16* __restrict__ hbf, u16* __restrict__ inbf,
    u16* __restrict__ wt, int* __restrict__ flag) {
    __shared__ float tile[32][33];
    int bid = blockIdx.x;
    int t = threadIdx.x;
    if (bid < 4096) {
        int idx = bid * 256 + t;
        int flat = idx << 2;
        int b = flat >> 10;
        int f = flat & 1023;
        const f32x4 x  = *(const f32x4*)(inputs + flat);
        const f32x4 c1 = *(const f32x4*)(cs + b * 4096 + 1024 + f);
        const f32x4 c2 = *(const f32x4*)(cs + b * 4096 + 2048 + f);
        const f32x4 c3 = *(const f32x4*)(cs + b * 4096 + 3072 + f);
        const f32x4 k0 = *(const f32x4*)(ck + f);
        const f32x4 k1 = *(const f32x4*)(ck + 1024 + f);
        const f32x4 k2 = *(const f32x4*)(ck + 2048 + f);
        const f32x4 k3 = *(const f32x4*)(ck + 3072 + f);
        const f32x4 bias = *(const f32x4*)(cb + f);
        const f32x4 h4 = *(const f32x4*)(h + flat);
        const f32x4 nv = *(const f32x4*)(n + flat);

        // any(n != 0): benign race, only 1 ever stored (plain store per wave)
        bool any = (nv[0] != 0.f) || (nv[1] != 0.f) || (nv[2] != 0.f) || (nv[3] != 0.f);
        unsigned long long msk = __ballot(any);
        if (msk && (t & 63) == 0) *flag = 1;

        u16x4 ca, hb, ib;
        #pragma unroll
        for (int q = 0; q < 4; ++q) {
            float v = c1[q] * k0[q] + c2[q] * k1[q] + c3[q] * k2[q] + x[q] * k3[q] + bias[q];
            float a = v / (1.f + expf(-v));   // silu
            ca[q] = f2bf(a);
            hb[q] = f2bf(h4[q]);
            ib[q] = f2bf(x[q]);
        }
        *(u16x4*)(convact + flat) = ca;
        *(u16x4*)(hbf + flat) = hb;
        *(u16x4*)(inbf + flat) = ib;

        float* ob = ncs_out + b * 4096 + f;
        *(f32x4*)(ob)        = c1;
        *(f32x4*)(ob + 1024) = c2;
        *(f32x4*)(ob + 2048) = c3;
        *(f32x4*)(ob + 3072) = x;
    } else {
        int wb = bid - 4096;          // 0..2047 = 64 tiles x 4 heads x 8 mats
        int gx = wb & 63;
        int hd = (wb >> 6) & 3;
        int mat = wb >> 8;
        const float* tab[8] = {W0, W1, W2, W3, W4, W5, W6, W7};
        const float* src = tab[mat] + hd * 65536;
        u16* dst = wt + (mat * 4 + hd) * 65536;
        int tx = t & 31, ty = t >> 5;
        int bx = (gx & 7) * 32;   // e tile
        int by = (gx >> 3) * 32;  // k tile
        #pragma unroll
        for (int r = 0; r < 4; ++r)
            tile[ty + r * 8][tx] = src[(by + ty + r * 8) * 256 + bx + tx];
        __syncthreads();
        #pragma unroll
        for (int r = 0; r < 4; ++r)
            dst[(bx + ty + r * 8) * 256 + by + tx] = f2bf(tile[tx][ty + r * 8]);
    }
}

// gates16[g][b][hd*256+e] = bf16( x_g . W_g + h . R_g + b_g )
// One block = full (gate, head) N=256 column range, M=128 rows, BK=64.
// 8 waves as 2 (wm) x 4 (wn), wave tile 64x64, acc 4x4 f32x4.
// grid: x = 32 (M/128), y = 16 (gsel*4 + head)
__global__ __launch_bounds__(512, 4) void kgemm(
    const u16* __restrict__ convact, const u16* __restrict__ inbf,
    const u16* __restrict__ hbf, const u16* __restrict__ wt,
    const float* __restrict__ bgi, const float* __restrict__ bgf,
    const float* __restrict__ bgz, const float* __restrict__ bgo,
    u16* __restrict__ gates16) {
    __shared__ u16 ldsA[128 * 64];   // 16 KB
    __shared__ u16 ldsB[256 * 64];   // 32 KB

    int t = threadIdx.x;
    int mtile = blockIdx.x;
    int pairidx = blockIdx.y;
    int gsel = pairidx >> 2;          // 0=i,1=f,2=z,3=o
    int hd = pairidx & 3;
    int row0 = mtile * 128;

    const u16* a0 = (gsel >= 2 ? inbf : convact) + row0 * 1024 + hd * 256;
    const u16* a1 = hbf + row0 * 1024 + hd * 256;
    const u16* b0 = wt + (gsel * 4 + hd) * 65536;         // W part [e][256k]
    const u16* b1 = wt + ((gsel + 4) * 4 + hd) * 65536;   // R part
    const float* bias = (gsel == 0 ? bgi : gsel == 1 ? bgf : gsel == 2 ? bgz : bgo) + hd * 256;

    f32x4 acc[4][4];
    #pragma unroll
    for (int i = 0; i < 4; ++i)
        #pragma unroll
        for (int j = 0; j < 4; ++j)
            acc[i][j] = (f32x4){0.f, 0.f, 0.f, 0.f};

    int lane = t & 63;
    int lr = lane & 15, lk = lane >> 4;
    int w = t >> 6;
    int wm = w >> 2, wn = w & 3;
    int wbase = t & ~63;   // wave-uniform granule base

    int arow = t >> 3, aseg = t & 7;   // granule decomposition (8 x 16B per 64-elem row)

    for (int ks = 0; ks < 8; ++ks) {
        int kb = ks * 64;
        const u16* ap = (kb < 256) ? (a0 + kb) : (a1 + (kb - 256));
        const u16* bp = (kb < 256) ? (b0 + kb) : (b1 + (kb - 256));
        __syncthreads();
        // stage A: [128 rows][64 k] bf16, 2 rounds of 512 x 16B lane-loads
        #pragma unroll
        for (int s = 0; s < 2; ++s) {
            int row = arow + s * 64;
            __builtin_amdgcn_global_load_lds(
                (const __attribute__((address_space(1))) void*)(ap + row * 1024 + aseg * 8),
                (__attribute__((address_space(3))) void*)(&ldsA[(wbase + s * 512) * 8]),
                16, 0, 0);
        }
        // stage B: [256 e][64 k] bf16, 4 rounds (row stride 256 in wt)
        #pragma unroll
        for (int s = 0; s < 4; ++s) {
            int row = arow + s * 64;
            __builtin_amdgcn_global_load_lds(
                (const __attribute__((address_space(1))) void*)(bp + row * 256 + aseg * 8),
                (__attribute__((address_space(3))) void*)(&ldsB[(wbase + s * 512) * 8]),
                16, 0, 0);
        }
        __syncthreads();

        #pragma unroll
        for (int kk = 0; kk < 2; ++kk) {
            bf16x8 a[4], bfr[4];
            #pragma unroll
            for (int mi = 0; mi < 4; ++mi)
                a[mi] = *(const bf16x8*)&ldsA[(wm * 64 + mi * 16 + lr) * 64 + kk * 32 + lk * 8];
            #pragma unroll
            for (int ni = 0; ni < 4; ++ni)
                bfr[ni] = *(const bf16x8*)&ldsB[(wn * 64 + ni * 16 + lr) * 64 + kk * 32 + lk * 8];
            #pragma unroll
            for (int mi = 0; mi < 4; ++mi)
                #pragma unroll
                for (int ni = 0; ni < 4; ++ni)
                    acc[mi][ni] = __builtin_amdgcn_mfma_f32_16x16x32_bf16(a[mi], bfr[ni], acc[mi][ni], 0, 0, 0);
        }
    }

    // epilogue: + bias, convert bf16, store
    float bv[4];
    #pragma unroll
    for (int ni = 0; ni < 4; ++ni)
        bv[ni] = bias[wn * 64 + ni * 16 + lr];

    u16* gout = gates16 + (size_t)gsel * BF_ELEMS;
    #pragma unroll
    for (int mi = 0; mi < 4; ++mi)
        #pragma unroll
        for (int ni = 0; ni < 4; ++ni)
            #pragma unroll
            for (int r = 0; r < 4; ++r) {
                int row = row0 + wm * 64 + mi * 16 + lk * 4 + r;
                int col = hd * 256 + wn * 64 + ni * 16 + lr;
                gout[row * 1024 + col] = f2bf(acc[mi][ni][r] + bv[ni]);
            }
}

// pointwise gate math + per-head LayerNorm; one block per row, one wave per head
__global__ __launch_bounds__(256) void kpoint(
    const u16* __restrict__ gates16,
    const float* __restrict__ c, const float* __restrict__ n, const float* __restrict__ m,
    const float* __restrict__ ln_scale, const int* __restrict__ flagp,
    float* __restrict__ out) {
    int b = blockIdx.x;
    int t = threadIdx.x;
    int l = t & 63;
    int j = (t >> 6) * 256 + l * 4;
    int idx = b * 1024 + j;
    int flag = *flagp;

    u16x4 iv = *(const u16x4*)(gates16 + idx);
    u16x4 fv = *(const u16x4*)(gates16 + (size_t)BF_ELEMS + idx);
    u16x4 zv = *(const u16x4*)(gates16 + 2 * (size_t)BF_ELEMS + idx);
    u16x4 ov = *(const u16x4*)(gates16 + 3 * (size_t)BF_ELEMS + idx);
    f32x4 cv = *(const f32x4*)(c + idx);
    f32x4 nv = *(const f32x4*)(n + idx);
    f32x4 mv = *(const f32x4*)(m + idx);
    f32x4 sc = *(const f32x4*)(ln_scale + j);

    f32x4 cn, nn, mn, hn;
    float s = 0.f, ss = 0.f;
    #pragma unroll
    for (int q = 0; q < 4; ++q) {
        float I = bf2f(iv[q]);
        float Fg = bf2f(fv[q]);
        float Z = bf2f(zv[q]);
        float O = bf2f(ov[q]);
        float og = 1.f / (1.f + expf(-O));
        float lf = (Fg >= 0.f) ? -log1pf(expf(-Fg)) : (Fg - log1pf(expf(Fg)));
        float mnew = flag ? fmaxf(lf + mv[q], I) : I;
        float ip = fminf(expf(I - mnew), 1.f);
        float fp = fminf(expf(lf + mv[q] - mnew), 1.f);
        float cnew = fp * cv[q] + ip * tanhf(Z);
        float nnew = fp * nv[q] + ip;
        float hnew = og * (cnew / fmaxf(nnew, 1e-6f));
        cn[q] = cnew; nn[q] = nnew; mn[q] = mnew; hn[q] = hnew;
        s += hnew; ss += hnew * hnew;
    }
    #pragma unroll
    for (int off = 32; off >= 1; off >>= 1) {
        s  += __shfl_xor(s, off);
        ss += __shfl_xor(ss, off);
    }
    float mu = s * (1.f / 256.f);
    float var = ss * (1.f / 256.f) - mu * mu;
    float rs = rsqrtf(var + 1e-6f);

    f32x4 o4;
    #pragma unroll
    for (int q = 0; q < 4; ++q)
        o4[q] = (hn[q] - mu) * rs * sc[q];

    *(f32x4*)(out + idx) = o4;
    *(f32x4*)(out + (size_t)BF_ELEMS + idx) = cn;
    *(f32x4*)(out + 2 * (size_t)BF_ELEMS + idx) = nn;
    *(f32x4*)(out + 3 * (size_t)BF_ELEMS + idx) = mn;
    *(f32x4*)(out + 4 * (size_t)BF_ELEMS + idx) = hn;
}

extern "C" void kernel_launch(void* const* d_in, const int* in_sizes, int n_in,
                              void* d_out, int out_size, void* d_ws, size_t ws_size,
                              hipStream_t stream) {
    const float* inputs = (const float*)d_in[0];
    const float* c = (const float*)d_in[1];
    const float* n = (const float*)d_in[2];
    const float* m = (const float*)d_in[3];
    const float* h = (const float*)d_in[4];
    const float* conv_state = (const float*)d_in[5];
    const float* conv_kernel = (const float*)d_in[6];
    const float* conv_bias = (const float*)d_in[7];
    const float* W[8];
    for (int i = 0; i < 8; ++i) W[i] = (const float*)d_in[8 + i];
    const float* bgi = (const float*)d_in[16];
    const float* bgf = (const float*)d_in[17];
    const float* bgz = (const float*)d_in[18];
    const float* bgo = (const float*)d_in[19];
    const float* ln_scale = (const float*)d_in[20];
    float* out = (float*)d_out;

    char* ws = (char*)d_ws;
    int* flag = (int*)ws;
    u16* convact = (u16*)(ws + 256);
    u16* hbf = convact + BF_ELEMS;
    u16* inbf = hbf + BF_ELEMS;
    u16* wt = inbf + BF_ELEMS;                       // 8*4*65536 bf16
    u16* gates16 = wt + (size_t)8 * 4 * 65536;       // 4 * BF_ELEMS bf16

    hipMemsetAsync(flag, 0, 4, stream);
    kprep<<<6144, 256, 0, stream>>>(inputs, conv_state, conv_kernel, conv_bias, h, n,
                                    W[0], W[1], W[2], W[3], W[4], W[5], W[6], W[7],
                                    out + 5 * (size_t)BF_ELEMS, convact, hbf, inbf, wt, flag);
    kgemm<<<dim3(32, 16), 512, 0, stream>>>(convact, inbf, hbf, wt,
                                            bgi, bgf, bgz, bgo, gates16);
    kpoint<<<4096, 256, 0, stream>>>(gates16, c, n, m, ln_scale, flag, out);
}

// Round 5
// 112.438 us; speedup vs baseline: 2.8295x; 1.0170x over previous
//
#include <hip/hip_runtime.h>

#define B_N 4096
#define F_N 1024
#define H_N 4
#define D_N 256
#define BF_ELEMS (B_N * F_N)   // 4194304

typedef unsigned short u16;
typedef __bf16 bf16x8 __attribute__((ext_vector_type(8)));
typedef float f32x4 __attribute__((ext_vector_type(4)));
typedef u16 u16x4 __attribute__((ext_vector_type(4)));

__device__ __forceinline__ u16 f2bf(float v) {
    union { float f; unsigned u; } x; x.f = v;
    unsigned r = x.u + 0x7fffu + ((x.u >> 16) & 1u);
    return (u16)(r >> 16);
}

__device__ __forceinline__ float bf2f(u16 v) {
    union { unsigned u; float f; } x; x.u = ((unsigned)v) << 16;
    return x.f;
}

// Fused prep: blocks 0..4095 = conv step + state shift + flag + bf16 casts;
// blocks 4096..6143 = weight f32->bf16 transpose [k][e] -> [e][k].
__global__ __launch_bounds__(256) void kprep(
    const float* __restrict__ inputs, const float* __restrict__ cs,
    const float* __restrict__ ck, const float* __restrict__ cb,
    const float* __restrict__ h, const float* __restrict__ n,
    const float* W0, const float* W1, const float* W2, const float* W3,
    const float* W4, const float* W5, const float* W6, const float* W7,
    float* __restrict__ ncs_out, u16* __restrict__ convact,
    u16* __restrict__ hbf, u16* __restrict__ inbf,
    u16* __restrict__ wt, int* __restrict__ flag) {
    __shared__ float tile[32][33];
    int bid = blockIdx.x;
    int t = threadIdx.x;
    if (bid < 4096) {
        int idx = bid * 256 + t;
        int flat = idx << 2;
        int b = flat >> 10;
        int f = flat & 1023;
        const f32x4 x  = *(const f32x4*)(inputs + flat);
        const f32x4 c1 = *(const f32x4*)(cs + b * 4096 + 1024 + f);
        const f32x4 c2 = *(const f32x4*)(cs + b * 4096 + 2048 + f);
        const f32x4 c3 = *(const f32x4*)(cs + b * 4096 + 3072 + f);
        const f32x4 k0 = *(const f32x4*)(ck + f);
        const f32x4 k1 = *(const f32x4*)(ck + 1024 + f);
        const f32x4 k2 = *(const f32x4*)(ck + 2048 + f);
        const f32x4 k3 = *(const f32x4*)(ck + 3072 + f);
        const f32x4 bias = *(const f32x4*)(cb + f);
        const f32x4 h4 = *(const f32x4*)(h + flat);
        const f32x4 nv = *(const f32x4*)(n + flat);

        // any(n != 0): benign race, only 1 ever stored (plain store per wave)
        bool any = (nv[0] != 0.f) || (nv[1] != 0.f) || (nv[2] != 0.f) || (nv[3] != 0.f);
        unsigned long long msk = __ballot(any);
        if (msk && (t & 63) == 0) *flag = 1;

        u16x4 ca, hb, ib;
        #pragma unroll
        for (int q = 0; q < 4; ++q) {
            float v = c1[q] * k0[q] + c2[q] * k1[q] + c3[q] * k2[q] + x[q] * k3[q] + bias[q];
            float a = v / (1.f + expf(-v));   // silu
            ca[q] = f2bf(a);
            hb[q] = f2bf(h4[q]);
            ib[q] = f2bf(x[q]);
        }
        *(u16x4*)(convact + flat) = ca;
        *(u16x4*)(hbf + flat) = hb;
        *(u16x4*)(inbf + flat) = ib;

        float* ob = ncs_out + b * 4096 + f;
        *(f32x4*)(ob)        = c1;
        *(f32x4*)(ob + 1024) = c2;
        *(f32x4*)(ob + 2048) = c3;
        *(f32x4*)(ob + 3072) = x;
    } else {
        int wb = bid - 4096;          // 0..2047 = 64 tiles x 4 heads x 8 mats
        int gx = wb & 63;
        int hd = (wb >> 6) & 3;
        int mat = wb >> 8;
        const float* tab[8] = {W0, W1, W2, W3, W4, W5, W6, W7};
        const float* src = tab[mat] + hd * 65536;
        u16* dst = wt + (mat * 4 + hd) * 65536;
        int tx = t & 31, ty = t >> 5;
        int bx = (gx & 7) * 32;   // e tile
        int by = (gx >> 3) * 32;  // k tile
        #pragma unroll
        for (int r = 0; r < 4; ++r)
            tile[ty + r * 8][tx] = src[(by + ty + r * 8) * 256 + bx + tx];
        __syncthreads();
        #pragma unroll
        for (int r = 0; r < 4; ++r)
            dst[(bx + ty + r * 8) * 256 + by + tx] = f2bf(tile[tx][ty + r * 8]);
    }
}

// gates16[g][b][hd*256+e] = bf16( x_g . W_g + h . R_g + b_g )
// 256x256 tile per block (one (gate,head) column range, 256 rows), BK=64,
// prefetch double-buffer (1 barrier/K-tile), XOR-swizzled LDS (granule ^ row&7,
// applied on BOTH the global_load_lds source and the ds_read address).
// 8 waves as 2 (wm) x 4 (wn): wave tile 128x64, acc 8x4 f32x4.
// grid: x = 16 (M/256), y = 16 (gsel*4 + head); 256 blocks = 1/CU.
__global__ __launch_bounds__(512, 2) void kgemm(
    const u16* __restrict__ convact, const u16* __restrict__ inbf,
    const u16* __restrict__ hbf, const u16* __restrict__ wt,
    const float* __restrict__ bgi, const float* __restrict__ bgf,
    const float* __restrict__ bgz, const float* __restrict__ bgo,
    u16* __restrict__ gates16) {
    __shared__ u16 ldsA[2][256 * 64];   // 64 KB
    __shared__ u16 ldsB[2][256 * 64];   // 64 KB

    int t = threadIdx.x;
    int mtile = blockIdx.x;
    int pairidx = blockIdx.y;
    int gsel = pairidx >> 2;          // 0=i,1=f,2=z,3=o
    int hd = pairidx & 3;
    int row0 = mtile * 256;

    const u16* a0 = (gsel >= 2 ? inbf : convact) + row0 * 1024 + hd * 256;
    const u16* a1 = hbf + row0 * 1024 + hd * 256;
    const u16* b0 = wt + (gsel * 4 + hd) * 65536;         // W part [e][256k]
    const u16* b1 = wt + ((gsel + 4) * 4 + hd) * 65536;   // R part
    const float* bias = (gsel == 0 ? bgi : gsel == 1 ? bgf : gsel == 2 ? bgz : bgo) + hd * 256;

    f32x4 acc[8][4];
    #pragma unroll
    for (int i = 0; i < 8; ++i)
        #pragma unroll
        for (int j = 0; j < 4; ++j)
            acc[i][j] = (f32x4){0.f, 0.f, 0.f, 0.f};

    int lane = t & 63;
    int lr = lane & 15, lk = lane >> 4;
    int w = t >> 6;
    int wm = w >> 2, wn = w & 3;
    int wbase = t & ~63;                       // wave-uniform granule base
    int srow = t >> 3;                         // staging row (0..63), +s*64
    int gsw = (t & 7) ^ ((t >> 3) & 7);        // swizzled source granule

    // Stage K-tile kt into buffer buf. Logical granule (row,g) lands at LDS
    // slot (row, g ^ (row&7)): linear dest granule s*512+t receives source
    // granule gsw of row srow+s*64 (row&7 invariant under +64).
    #define STAGE_TILE(buf, kt) do {                                              \
        int kb = (kt) * 64;                                                       \
        const u16* ap = (kb < 256) ? (a0 + kb) : (a1 + (kb - 256));               \
        const u16* bp = (kb < 256) ? (b0 + kb) : (b1 + (kb - 256));               \
        _Pragma("unroll")                                                         \
        for (int s = 0; s < 4; ++s) {                                             \
            int row = srow + s * 64;                                              \
            __builtin_amdgcn_global_load_lds(                                     \
                (const __attribute__((address_space(1))) void*)(ap + row * 1024 + gsw * 8), \
                (__attribute__((address_space(3))) void*)(&ldsA[buf][(s * 512 + wbase) * 8]), \
                16, 0, 0);                                                        \
        }                                                                         \
        _Pragma("unroll")                                                         \
        for (int s = 0; s < 4; ++s) {                                             \
            int row = srow + s * 64;                                              \
            __builtin_amdgcn_global_load_lds(                                     \
                (const __attribute__((address_space(1))) void*)(bp + row * 256 + gsw * 8), \
                (__attribute__((address_space(3))) void*)(&ldsB[buf][(s * 512 + wbase) * 8]), \
                16, 0, 0);                                                        \
        }                                                                         \
    } while (0)

    STAGE_TILE(0, 0);
    __syncthreads();

    for (int kt = 0; kt < 8; ++kt) {
        int buf = kt & 1;
        if (kt < 7) STAGE_TILE(buf ^ 1, kt + 1);

        #pragma unroll
        for (int kk = 0; kk < 2; ++kk) {
            bf16x8 a[8], bb[4];
            #pragma unroll
            for (int mi = 0; mi < 8; ++mi) {
                int row = wm * 128 + mi * 16 + lr;
                a[mi] = *(const bf16x8*)&ldsA[buf][row * 64 + (((kk * 4 + lk) ^ (lr & 7)) * 8)];
            }
            #pragma unroll
            for (int ni = 0; ni < 4; ++ni) {
                int row = wn * 64 + ni * 16 + lr;
                bb[ni] = *(const bf16x8*)&ldsB[buf][row * 64 + (((kk * 4 + lk) ^ (lr & 7)) * 8)];
            }
            #pragma unroll
            for (int mi = 0; mi < 8; ++mi)
                #pragma unroll
                for (int ni = 0; ni < 4; ++ni)
                    acc[mi][ni] = __builtin_amdgcn_mfma_f32_16x16x32_bf16(a[mi], bb[ni], acc[mi][ni], 0, 0, 0);
        }
        __syncthreads();   // drains vmcnt(0): this iter's prefetch has landed
    }

    // epilogue: + bias, convert bf16, store
    float bv[4];
    #pragma unroll
    for (int ni = 0; ni < 4; ++ni)
        bv[ni] = bias[wn * 64 + ni * 16 + lr];

    u16* gout = gates16 + (size_t)gsel * BF_ELEMS;
    #pragma unroll
    for (int mi = 0; mi < 8; ++mi)
        #pragma unroll
        for (int ni = 0; ni < 4; ++ni)
            #pragma unroll
            for (int r = 0; r < 4; ++r) {
                int row = row0 + wm * 128 + mi * 16 + lk * 4 + r;
                int col = hd * 256 + wn * 64 + ni * 16 + lr;
                gout[row * 1024 + col] = f2bf(acc[mi][ni][r] + bv[ni]);
            }
    #undef STAGE_TILE
}

// pointwise gate math + per-head LayerNorm; one block per row, one wave per head
__global__ __launch_bounds__(256) void kpoint(
    const u16* __restrict__ gates16,
    const float* __restrict__ c, const float* __restrict__ n, const float* __restrict__ m,
    const float* __restrict__ ln_scale, const int* __restrict__ flagp,
    float* __restrict__ out) {
    int b = blockIdx.x;
    int t = threadIdx.x;
    int l = t & 63;
    int j = (t >> 6) * 256 + l * 4;
    int idx = b * 1024 + j;
    int flag = *flagp;

    u16x4 iv = *(const u16x4*)(gates16 + idx);
    u16x4 fv = *(const u16x4*)(gates16 + (size_t)BF_ELEMS + idx);
    u16x4 zv = *(const u16x4*)(gates16 + 2 * (size_t)BF_ELEMS + idx);
    u16x4 ov = *(const u16x4*)(gates16 + 3 * (size_t)BF_ELEMS + idx);
    f32x4 cv = *(const f32x4*)(c + idx);
    f32x4 nv = *(const f32x4*)(n + idx);
    f32x4 mv = *(const f32x4*)(m + idx);
    f32x4 sc = *(const f32x4*)(ln_scale + j);

    f32x4 cn, nn, mn, hn;
    float s = 0.f, ss = 0.f;
    #pragma unroll
    for (int q = 0; q < 4; ++q) {
        float I = bf2f(iv[q]);
        float Fg = bf2f(fv[q]);
        float Z = bf2f(zv[q]);
        float O = bf2f(ov[q]);
        float og = 1.f / (1.f + expf(-O));
        float lf = (Fg >= 0.f) ? -log1pf(expf(-Fg)) : (Fg - log1pf(expf(Fg)));
        float mnew = flag ? fmaxf(lf + mv[q], I) : I;
        float ip = fminf(expf(I - mnew), 1.f);
        float fp = fminf(expf(lf + mv[q] - mnew), 1.f);
        float cnew = fp * cv[q] + ip * tanhf(Z);
        float nnew = fp * nv[q] + ip;
        float hnew = og * (cnew / fmaxf(nnew, 1e-6f));
        cn[q] = cnew; nn[q] = nnew; mn[q] = mnew; hn[q] = hnew;
        s += hnew; ss += hnew * hnew;
    }
    #pragma unroll
    for (int off = 32; off >= 1; off >>= 1) {
        s  += __shfl_xor(s, off);
        ss += __shfl_xor(ss, off);
    }
    float mu = s * (1.f / 256.f);
    float var = ss * (1.f / 256.f) - mu * mu;
    float rs = rsqrtf(var + 1e-6f);

    f32x4 o4;
    #pragma unroll
    for (int q = 0; q < 4; ++q)
        o4[q] = (hn[q] - mu) * rs * sc[q];

    *(f32x4*)(out + idx) = o4;
    *(f32x4*)(out + (size_t)BF_ELEMS + idx) = cn;
    *(f32x4*)(out + 2 * (size_t)BF_ELEMS + idx) = nn;
    *(f32x4*)(out + 3 * (size_t)BF_ELEMS + idx) = mn;
    *(f32x4*)(out + 4 * (size_t)BF_ELEMS + idx) = hn;
}

extern "C" void kernel_launch(void* const* d_in, const int* in_sizes, int n_in,
                              void* d_out, int out_size, void* d_ws, size_t ws_size,
                              hipStream_t stream) {
    const float* inputs = (const float*)d_in[0];
    const float* c = (const float*)d_in[1];
    const float* n = (const float*)d_in[2];
    const float* m = (const float*)d_in[3];
    const float* h = (const float*)d_in[4];
    const float* conv_state = (const float*)d_in[5];
    const float* conv_kernel = (const float*)d_in[6];
    const float* conv_bias = (const float*)d_in[7];
    const float* W[8];
    for (int i = 0; i < 8; ++i) W[i] = (const float*)d_in[8 + i];
    const float* bgi = (const float*)d_in[16];
    const float* bgf = (const float*)d_in[17];
    const float* bgz = (const float*)d_in[18];
    const float* bgo = (const float*)d_in[19];
    const float* ln_scale = (const float*)d_in[20];
    float* out = (float*)d_out;

    char* ws = (char*)d_ws;
    int* flag = (int*)ws;
    u16* convact = (u16*)(ws + 256);
    u16* hbf = convact + BF_ELEMS;
    u16* inbf = hbf + BF_ELEMS;
    u16* wt = inbf + BF_ELEMS;                       // 8*4*65536 bf16
    u16* gates16 = wt + (size_t)8 * 4 * 65536;       // 4 * BF_ELEMS bf16

    hipMemsetAsync(flag, 0, 4, stream);
    kprep<<<6144, 256, 0, stream>>>(inputs, conv_state, conv_kernel, conv_bias, h, n,
                                    W[0], W[1], W[2], W[3], W[4], W[5], W[6], W[7],
                                    out + 5 * (size_t)BF_ELEMS, convact, hbf, inbf, wt, flag);
    kgemm<<<dim3(16, 16), 512, 0, stream>>>(convact, inbf, hbf, wt,
                                            bgi, bgf, bgz, bgo, gates16);
    kpoint<<<4096, 256, 0, stream>>>(gates16, c, n, m, ln_scale, flag, out);
}